// Round 14
// baseline (137.569 us; speedup 1.0000x reference)
//
#include <hip/hip_runtime.h>
#include <hip/hip_fp8.h>

typedef float  float4_t __attribute__((ext_vector_type(4)));
typedef unsigned int uint2_t __attribute__((ext_vector_type(2)));
typedef float  f32x4   __attribute__((ext_vector_type(4)));
typedef int    int4_t  __attribute__((ext_vector_type(4)));

#define FEAT   256
#define BANK   2048
#define NROWS  2048       // 256 anchors * 8 views
#define NPAN   576        // 64-col panels over 36864 cols
#define NSLOT  192        // wave slots = NPAN / 3 panels-per-wave
#define EXP2K  14.4269504088896f   // 10*log2(e); A pre-scaled by this in pass0
#define LN2F   0.69314718055995f   // logit = acc * LN2F  (acc = EXP2K * dot)
#define A_CH8  65536      // A 8-byte chunks: 64 strips * 2 mi * 8 ks * 64 lanes
#define B_CH8  1179648    // B 8-byte chunks: 576 panels * 32 frags * 64 lanes
#define TOT8   (A_CH8 + B_CH8)

__device__ inline unsigned char to_fp8(float x) {
    __hip_fp8_e4m3 f(x);
    return *reinterpret_cast<unsigned char*>(&f);
}

// 16-lane (DPP row) sum: every lane of each 16-lane group gets the group total.
__device__ inline float rowsum16(float x) {
    float t;
    asm("s_nop 1\n\tv_add_f32 %0, %1, %1 row_ror:1"  : "=v"(t) : "v"(x)); x = t;
    asm("s_nop 1\n\tv_add_f32 %0, %1, %1 row_ror:2"  : "=v"(t) : "v"(x)); x = t;
    asm("s_nop 1\n\tv_add_f32 %0, %1, %1 row_ror:4"  : "=v"(t) : "v"(x)); x = t;
    asm("s_nop 1\n\tv_add_f32 %0, %1, %1 row_ror:8"  : "=v"(t) : "v"(x)); x = t;
    return x;
}

// Pass 0: fp32 -> fp8 e4m3 ONCE, MFMA fragment order. A is PRE-SCALED by
// EXP2K (fp8 is a float format: scaling costs no relative precision), so
// pass1's epilogue needs no per-logit multiply: exp(10*dot) = exp2(acc).
__global__ __launch_bounds__(256) void pass0_pack(
    const float* __restrict__ X,    // X_anchor [256][8][256]
    const float* __restrict__ Q,    // queue [19][2048][256]
    unsigned char* __restrict__ Abuf,
    unsigned char* __restrict__ Bbuf,
    float* __restrict__ out)
{
    const int cid = blockIdx.x * 256 + threadIdx.x;
    if (cid == 0) out[0] = 0.0f;
    if (cid >= TOT8) return;
    const int lane = cid & 63;
    const int ks   = (cid >> 6) & 7;
    const int k    = ks * 32 + ((lane >> 4) << 3);
    const float* src;
    unsigned char* dst;
    float scale;
    if (cid < A_CH8) {
        const int mi = (cid >> 9) & 1, s = cid >> 10;
        const int r  = s * 32 + mi * 16 + (lane & 15);      // anchor row = v*256+a
        src = X + ((size_t)((r & 255) * 8 + (r >> 8))) * FEAT + k;
        dst = Abuf + ((size_t)cid << 3);
        scale = EXP2K;
    } else {
        const int b = cid - A_CH8;
        const int ni = (b >> 9) & 3, p = b >> 11;
        const int col = p * 64 + ni * 16 + (lane & 15);     // class 0 skipped
        src = Q + ((size_t)(BANK + col)) * FEAT + k;
        dst = Bbuf + ((size_t)b << 3);
        scale = 1.0f;
    }
    float4_t v0 = *(const float4_t*)src;
    float4_t v1 = *(const float4_t*)(src + 4);
    const unsigned int b0 = to_fp8(v0.x * scale) | ((unsigned int)to_fp8(v0.y * scale) << 8)
                          | ((unsigned int)to_fp8(v0.z * scale) << 16) | ((unsigned int)to_fp8(v0.w * scale) << 24);
    const unsigned int b1 = to_fp8(v1.x * scale) | ((unsigned int)to_fp8(v1.y * scale) << 8)
                          | ((unsigned int)to_fp8(v1.z * scale) << 16) | ((unsigned int)to_fp8(v1.w * scale) << 24);
    uint2_t u = { b0, b1 };
    *(uint2_t*)dst = u;
}

// Pass 1: R12 structure (barrier-free, single b[4][8], 3 panels/wave) +
// cross-panel register accumulation (one DPP/store block per wave) +
// mul-free epilogue (A pre-scaled).
__global__ __launch_bounds__(256, 3) void pass1_gemm(
    const unsigned char* __restrict__ Abuf,
    const unsigned char* __restrict__ Bbuf,
    const int*   __restrict__ y,
    float* __restrict__ partS,  // [NROWS][NSLOT] exp-sum over wave's 3 panels
    float* __restrict__ partE,  // [NROWS][NSLOT] exp-sum over pos panels only
    float* __restrict__ partL,  // [NROWS][NSLOT] logit-sum over pos panels
    float* __restrict__ diagL)  // [NROWS]
{
    // XCD-banded: xcd owns panels [xcd*72, xcd*72+72)
    const int bid   = blockIdx.x;
    const int xcd   = bid & 7;
    const int j     = bid >> 3;            // 0..383
    const int strip = j & 63;              // 32-row strip
    const int pg    = xcd * 6 + (j >> 6);  // 0..47 (12 panels each)

    const int t = threadIdx.x, lane = t & 63, w = t >> 6;
    const int g = lane >> 4, ci = lane & 15;
    const int slot = pg * 4 + w;           // 0..191

    // ---- A fragments in registers (32 rows x 256 K fp8 = 32 VGPR) ----
    const long* Ap = (const long*)(Abuf + ((size_t)strip << 13));
    long a[2][8];
    #pragma unroll
    for (int mi = 0; mi < 2; ++mi)
        #pragma unroll
        for (int ks = 0; ks < 8; ++ks)
            a[mi][ks] = Ap[((mi << 3) | ks) * 64 + lane];

    // ---- per-lane row classes ----
    int4_t yv[2];
    #pragma unroll
    for (int mi = 0; mi < 2; ++mi)
        yv[mi] = *(const int4_t*)(y + ((strip * 32 + mi * 16 + g * 4) & 255));

    const int pd = strip >> 1;                     // panel containing diag cols
    const int dsub = (strip & 1) * 32;             // col offset of row 0 in pd

    float sAll[2][4] = {}, sPos[2][4] = {}, lPos[2][4] = {};

    #pragma unroll 1
    for (int pi = 0; pi < 3; ++pi) {
        const int p  = pg * 12 + w * 3 + pi;
        const int cj = (p >> 5) + 1;               // class of this panel (1..18)
        const long* Bp = (const long*)(Bbuf + ((size_t)p << 14));

        long b[4][8];
        #pragma unroll
        for (int ni = 0; ni < 4; ++ni)
            #pragma unroll
            for (int ks = 0; ks < 8; ++ks)
                b[ni][ks] = Bp[((ni << 3) | ks) * 64 + lane];

        f32x4 acc[2][4] = {};
        #pragma unroll
        for (int ni = 0; ni < 4; ++ni)
            #pragma unroll
            for (int ks = 0; ks < 8; ++ks) {
                acc[0][ni] = __builtin_amdgcn_mfma_f32_16x16x32_fp8_fp8(
                    a[0][ks], b[ni][ks], acc[0][ni], 0, 0, 0);
                acc[1][ni] = __builtin_amdgcn_mfma_f32_16x16x32_fp8_fp8(
                    a[1][ks], b[ni][ks], acc[1][ni], 0, 0, 0);
            }

        // ---- epilogue: mul-free exp2; accumulate in regs across panels ----
        #pragma unroll
        for (int mi = 0; mi < 2; ++mi) {
            #pragma unroll
            for (int rj = 0; rj < 4; ++rj) {
                const bool isPos = (yv[mi][rj] == cj);
                float rs = 0.0f, lp = 0.0f;
                #pragma unroll
                for (int ni = 0; ni < 4; ++ni) {
                    const float av = acc[mi][ni][rj];
                    rs += __builtin_exp2f(av);
                    if (isPos) lp += av;
                    if (p == pd && (ni * 16 + ci) == (dsub + mi * 16 + g * 4 + rj))
                        diagL[strip * 32 + mi * 16 + g * 4 + rj] = av * LN2F;
                }
                sAll[mi][rj] += rs;
                if (isPos) { sPos[mi][rj] += rs; lPos[mi][rj] += lp; }
            }
        }
    }

    // ---- one DPP reduce + store block per wave ----
    #pragma unroll
    for (int mi = 0; mi < 2; ++mi) {
        #pragma unroll
        for (int rj = 0; rj < 4; ++rj) {
            const float vS = rowsum16(sAll[mi][rj]);
            const float vE = rowsum16(sPos[mi][rj]);
            const float vL = rowsum16(lPos[mi][rj]);
            if (ci == 0) {
                const int r = strip * 32 + mi * 16 + g * 4 + rj;
                partS[(size_t)r * NSLOT + slot] = vS;
                partE[(size_t)r * NSLOT + slot] = vE;
                partL[(size_t)r * NSLOT + slot] = vL * LN2F;
            }
        }
    }
}

// Pass 3: per-row finish. S/E1/Lp = sums over 192 slots; neg = S - E1 + 2048;
// loss_r = ln(neg) - Lp'/m (m=2047 & diag removed for c==1).
__global__ __launch_bounds__(256) void pass3_kernel(
    const int* __restrict__ y,
    const float* __restrict__ partS, const float* __restrict__ partE,
    const float* __restrict__ partL,
    const float* __restrict__ diagL, float* __restrict__ out)
{
    __shared__ float sh[4];
    const int r = blockIdx.x * 256 + threadIdx.x;
    const int c = y[r & 255];

    const float4_t* ps = (const float4_t*)(partS + (size_t)r * NSLOT);
    const float4_t* pe = (const float4_t*)(partE + (size_t)r * NSLOT);
    const float4_t* pl = (const float4_t*)(partL + (size_t)r * NSLOT);
    float S = 0.0f, E1 = 0.0f, Lp = 0.0f;
    #pragma unroll 4
    for (int q = 0; q < NSLOT / 4; ++q) {
        const float4_t vs = ps[q], ve = pe[q], vl = pl[q];
        S  += vs.x + vs.y + vs.z + vs.w;
        E1 += ve.x + ve.y + ve.z + ve.w;
        Lp += vl.x + vl.y + vl.z + vl.w;
    }
    float m = 2048.0f;
    if (c == 1) { Lp -= diagL[r]; m = 2047.0f; }
    const float neg = S - E1 + 2048.0f;
    float lr = __logf(neg) - Lp / m;

    #pragma unroll
    for (int mm = 1; mm < 64; mm <<= 1) lr += __shfl_xor(lr, mm);
    const int w = threadIdx.x >> 6;
    if ((threadIdx.x & 63) == 0) sh[w] = lr;
    __syncthreads();
    if (threadIdx.x == 0)
        atomicAdd(out, (sh[0] + sh[1] + sh[2] + sh[3]) * (1.0f / (float)NROWS));
}

extern "C" void kernel_launch(void* const* d_in, const int* in_sizes, int n_in,
                              void* d_out, int out_size, void* d_ws, size_t ws_size,
                              hipStream_t stream) {
    const float* X = (const float*)d_in[0];
    const int*   y = (const int*)d_in[1];
    const float* Q = (const float*)d_in[2];
    float* out   = (float*)d_out;
    float* partS = (float*)d_ws;                                // 2048*192 f32 (1.57 MB)
    float* partE = partS + (size_t)NROWS * NSLOT;               // 1.57 MB
    float* partL = partE + (size_t)NROWS * NSLOT;               // 1.57 MB
    float* diagL = partL + (size_t)NROWS * NSLOT;               // 8 KB
    unsigned char* Abuf = (unsigned char*)(diagL + NROWS);      // 512 KB
    unsigned char* Bbuf = Abuf + ((size_t)A_CH8 << 3);          // 9.44 MB

    pass0_pack<<<dim3(TOT8 / 256), dim3(256), 0, stream>>>(X, Q, Abuf, Bbuf, out);
    pass1_gemm<<<dim3(64 * 48), dim3(256), 0, stream>>>(Abuf, Bbuf, y, partS, partE, partL, diagL);
    pass3_kernel<<<dim3(NROWS / 256), dim3(256), 0, stream>>>(y, partS, partE, partL, diagL, out);
}

// Round 15
// 112.967 us; speedup vs baseline: 1.2178x; 1.2178x over previous
//
#include <hip/hip_runtime.h>
#include <hip/hip_fp8.h>

typedef float  float4_t __attribute__((ext_vector_type(4)));
typedef unsigned int uint2_t __attribute__((ext_vector_type(2)));
typedef float  f32x4   __attribute__((ext_vector_type(4)));

#define FEAT   256
#define BANK   2048
#define NROWS  2048       // 256 anchors * 8 views
#define NPAN   576        // 64-col panels over 36864 cols
#define NCLS   18
#define CSPLIT 16         // m-chunks per class for csum partials
#define EXP2K  14.4269504088896f   // 10*log2(e); A pre-scaled -> exp(10 dot)=exp2(acc)
#define A_CH8  65536      // A 8-byte chunks: 64 strips * 2 mi * 8 ks * 64 lanes
#define B_CH8  1179648    // B 8-byte chunks: 576 panels * 32 frags * 64 lanes
#define TOT8   (A_CH8 + B_CH8)

__device__ inline unsigned char to_fp8(float x) {
    __hip_fp8_e4m3 f(x);
    return *reinterpret_cast<unsigned char*>(&f);
}

// 16-lane (DPP row) sum: every lane of each 16-lane group gets the group total.
__device__ inline float rowsum16(float x) {
    float t;
    asm("s_nop 1\n\tv_add_f32 %0, %1, %1 row_ror:1"  : "=v"(t) : "v"(x)); x = t;
    asm("s_nop 1\n\tv_add_f32 %0, %1, %1 row_ror:2"  : "=v"(t) : "v"(x)); x = t;
    asm("s_nop 1\n\tv_add_f32 %0, %1, %1 row_ror:4"  : "=v"(t) : "v"(x)); x = t;
    asm("s_nop 1\n\tv_add_f32 %0, %1, %1 row_ror:8"  : "=v"(t) : "v"(x)); x = t;
    return x;
}

// Pass 0: fp32 -> fp8 e4m3 ONCE, MFMA fragment order; A pre-scaled by EXP2K.
__global__ __launch_bounds__(256) void pass0_pack(
    const float* __restrict__ X,    // X_anchor [256][8][256]
    const float* __restrict__ Q,    // queue [19][2048][256]
    unsigned char* __restrict__ Abuf,
    unsigned char* __restrict__ Bbuf,
    float* __restrict__ out)
{
    const int cid = blockIdx.x * 256 + threadIdx.x;
    if (cid == 0) out[0] = 0.0f;
    if (cid >= TOT8) return;
    const int lane = cid & 63;
    const int ks   = (cid >> 6) & 7;
    const int k    = ks * 32 + ((lane >> 4) << 3);
    const float* src;
    unsigned char* dst;
    float scale;
    if (cid < A_CH8) {
        const int mi = (cid >> 9) & 1, s = cid >> 10;
        const int r  = s * 32 + mi * 16 + (lane & 15);      // anchor row = v*256+a
        src = X + ((size_t)((r & 255) * 8 + (r >> 8))) * FEAT + k;
        dst = Abuf + ((size_t)cid << 3);
        scale = EXP2K;
    } else {
        const int b = cid - A_CH8;
        const int ni = (b >> 9) & 3, p = b >> 11;
        const int col = p * 64 + ni * 16 + (lane & 15);     // class 0 skipped
        src = Q + ((size_t)(BANK + col)) * FEAT + k;
        dst = Bbuf + ((size_t)b << 3);
        scale = 1.0f;
    }
    float4_t v0 = *(const float4_t*)src;
    float4_t v1 = *(const float4_t*)(src + 4);
    const unsigned int b0 = to_fp8(v0.x * scale) | ((unsigned int)to_fp8(v0.y * scale) << 8)
                          | ((unsigned int)to_fp8(v0.z * scale) << 16) | ((unsigned int)to_fp8(v0.w * scale) << 24);
    const unsigned int b1 = to_fp8(v1.x * scale) | ((unsigned int)to_fp8(v1.y * scale) << 8)
                          | ((unsigned int)to_fp8(v1.z * scale) << 16) | ((unsigned int)to_fp8(v1.w * scale) << 24);
    uint2_t u = { b0, b1 };
    *(uint2_t*)dst = u;
}

// Pass 2: per-class column sums of Q (f32 exact), split over CSPLIT m-chunks.
// csumPart[(c*CSPLIT+i)][k] = sum_{m in chunk i} Q[c+1][m][k]
__global__ __launch_bounds__(256) void pass2_csum(
    const float* __restrict__ Q, float* __restrict__ csumPart)
{
    const int c = blockIdx.x >> 4;        // 0..17 -> class c+1
    const int i = blockIdx.x & 15;
    const int k = threadIdx.x;
    const float* base = Q + ((size_t)(c + 1) * BANK + (size_t)i * (BANK / CSPLIT)) * FEAT + k;
    float s = 0.0f;
    #pragma unroll 4
    for (int m = 0; m < BANK / CSPLIT; ++m) s += base[(size_t)m * FEAT];
    csumPart[((size_t)(c * CSPLIT + i)) * FEAT + k] = s;
}

// Pass 1: barrier-free streaming fp8 GEMM, divergence-free epilogue.
// Wave: A (32 rows x K=256) pinned in 32 VGPR; 3 panels; per-ni-pair B loads
// (32 VGPR in flight); epilogue = exp2 + 8 DPP chains + uniform partS store.
// No y, no pos logic, no diag. ~105 VGPR -> 4 waves/SIMD.
__global__ __launch_bounds__(256, 4) void pass1_gemm(
    const unsigned char* __restrict__ Abuf,
    const unsigned char* __restrict__ Bbuf,
    float* __restrict__ partS)  // [NPAN][NROWS]
{
    // XCD-banded: xcd owns panels [xcd*72, xcd*72+72)
    const int bid   = blockIdx.x;
    const int xcd   = bid & 7;
    const int j     = bid >> 3;            // 0..383
    const int strip = j & 63;              // 32-row strip
    const int pg    = xcd * 6 + (j >> 6);  // 0..47 (12 panels each)

    const int t = threadIdx.x, lane = t & 63, w = t >> 6;
    const int g = lane >> 4, ci = lane & 15;

    // ---- A fragments in registers (32 rows x 256 K fp8 = 32 VGPR) ----
    const long* Ap = (const long*)(Abuf + ((size_t)strip << 13));
    long a[2][8];
    #pragma unroll
    for (int mi = 0; mi < 2; ++mi)
        #pragma unroll
        for (int ks = 0; ks < 8; ++ks)
            a[mi][ks] = Ap[((mi << 3) | ks) * 64 + lane];

    #pragma unroll 1
    for (int pi = 0; pi < 3; ++pi) {
        const int p = pg * 12 + w * 3 + pi;
        const long* Bp = (const long*)(Bbuf + ((size_t)p << 14));
        float rs[2][4] = {};
        #pragma unroll
        for (int nh = 0; nh < 2; ++nh) {           // two ni-pairs
            long b[2][8];
            #pragma unroll
            for (int nn = 0; nn < 2; ++nn)
                #pragma unroll
                for (int ks = 0; ks < 8; ++ks)
                    b[nn][ks] = Bp[((((nh << 1) | nn) << 3) | ks) * 64 + lane];
            f32x4 acc[2][2] = {};
            #pragma unroll
            for (int ks = 0; ks < 8; ++ks)
                #pragma unroll
                for (int nn = 0; nn < 2; ++nn) {
                    acc[0][nn] = __builtin_amdgcn_mfma_f32_16x16x32_fp8_fp8(
                        a[0][ks], b[nn][ks], acc[0][nn], 0, 0, 0);
                    acc[1][nn] = __builtin_amdgcn_mfma_f32_16x16x32_fp8_fp8(
                        a[1][ks], b[nn][ks], acc[1][nn], 0, 0, 0);
                }
            #pragma unroll
            for (int mi = 0; mi < 2; ++mi)
                #pragma unroll
                for (int rj = 0; rj < 4; ++rj)
                    rs[mi][rj] += __builtin_exp2f(acc[mi][0][rj])
                                + __builtin_exp2f(acc[mi][1][rj]);
        }
        #pragma unroll
        for (int mi = 0; mi < 2; ++mi)
            #pragma unroll
            for (int rj = 0; rj < 4; ++rj) {
                const float v = rowsum16(rs[mi][rj]);
                if (ci == 0)
                    partS[(size_t)p * NROWS + strip * 32 + mi * 16 + g * 4 + rj] = v;
            }
    }
}

// Pass 3: reduce csumPart -> LDS; per row: S/E1 from partS band; Lp via f32
// 256-dot with class-sum; diag dot for class-1 rows; loss = ln(neg) - Lp'/m.
__global__ __launch_bounds__(256) void pass3_kernel(
    const int* __restrict__ y,
    const float* __restrict__ partS, const float* __restrict__ csumPart,
    const float* __restrict__ X, const float* __restrict__ Q,
    float* __restrict__ out)
{
    __shared__ float csumLDS[NCLS * 257];   // +1 pad: bank = (c+k)%32
    __shared__ float sh[4];
    const int t = threadIdx.x;
    for (int idx = t; idx < NCLS * FEAT; idx += 256) {
        const int c = idx >> 8, k = idx & 255;
        float s = 0.0f;
        #pragma unroll
        for (int i = 0; i < CSPLIT; ++i)
            s += csumPart[((size_t)(c * CSPLIT + i)) * FEAT + k];
        csumLDS[c * 257 + k] = s;
    }
    __syncthreads();

    const int r = blockIdx.x * 256 + t;
    const int c = y[r & 255];
    float S = 0.0f, E1 = 0.0f;
    const int p0 = (c - 1) * 32, p1 = c * 32;
    for (int p = 0; p < NPAN; ++p) {
        const float v = partS[(size_t)p * NROWS + r];
        S += v;
        if (p >= p0 && p < p1) E1 += v;
    }
    const float* Xrow = X + ((size_t)((r & 255) * 8 + (r >> 8))) * FEAT;
    const float* cs = &csumLDS[(c - 1) * 257];
    float dot = 0.0f;
    for (int k = 0; k < FEAT; ++k) dot += Xrow[k] * cs[k];
    float Lp = 10.0f * dot;
    float m = 2048.0f;
    if (c == 1) {
        const float* Qr = Q + ((size_t)(BANK + r)) * FEAT;
        float d = 0.0f;
        for (int k = 0; k < FEAT; ++k) d += Xrow[k] * Qr[k];
        Lp -= 10.0f * d;
        m = 2047.0f;
    }
    const float neg = S - E1 + 2048.0f;
    float lr = __logf(neg) - Lp / m;

    #pragma unroll
    for (int mm = 1; mm < 64; mm <<= 1) lr += __shfl_xor(lr, mm);
    const int w = t >> 6;
    if ((t & 63) == 0) sh[w] = lr;
    __syncthreads();
    if (t == 0)
        atomicAdd(out, (sh[0] + sh[1] + sh[2] + sh[3]) * (1.0f / (float)NROWS));
}

extern "C" void kernel_launch(void* const* d_in, const int* in_sizes, int n_in,
                              void* d_out, int out_size, void* d_ws, size_t ws_size,
                              hipStream_t stream) {
    const float* X = (const float*)d_in[0];
    const int*   y = (const int*)d_in[1];
    const float* Q = (const float*)d_in[2];
    float* out      = (float*)d_out;
    float* partS    = (float*)d_ws;                             // 576*2048 f32 (4.72 MB)
    float* csumPart = partS + (size_t)NPAN * NROWS;             // 18*16*256 f32 (295 KB)
    unsigned char* Abuf = (unsigned char*)(csumPart + (size_t)NCLS * CSPLIT * FEAT); // 512 KB
    unsigned char* Bbuf = Abuf + ((size_t)A_CH8 << 3);          // 9.44 MB

    pass0_pack<<<dim3(TOT8 / 256), dim3(256), 0, stream>>>(X, Q, Abuf, Bbuf, out);
    pass2_csum<<<dim3(NCLS * CSPLIT), dim3(256), 0, stream>>>(Q, csumPart);
    pass1_gemm<<<dim3(64 * 48), dim3(256), 0, stream>>>(Abuf, Bbuf, partS);
    pass3_kernel<<<dim3(NROWS / 256), dim3(256), 0, stream>>>(y, partS, csumPart, X, Q, out);
}